// Round 9
// baseline (29.421 us; speedup 1.0000x reference)
//
#include <hip/hip_runtime.h>
#include <cstdint>
#include <cstddef>

// out[b,c,h,w] = sum_nb x[b, rp[c][nb], h, w] * 2^nb ; x in {0.0,1.0} exactly.
constexpr int Bn = 16;
constexpr int TBn = 64;
constexpr int Cn = 64;
constexpr int HW = 128 * 128;                 // 16384 pixels per (b, plane)
constexpr int TOTAL_PIX = Bn * HW;            // 262144
constexpr int PIX_PER_TILE = 128;             // 32 float4-groups per tile
constexpr int PIX_PER_BLOCK = 256;            // two tiles per block
constexpr int BLOCKS = TOTAL_PIX / PIX_PER_BLOCK;   // 1024
constexpr int MROW_DW = 10;                   // 8 u32 payload + 2 pad

typedef const __attribute__((address_space(1))) void g_void;
typedef __attribute__((address_space(3))) void l_void;

__global__ __launch_bounds__(256) void rp_pack_pipe(
    const float* __restrict__ x,
    const int* __restrict__ rp,
    float* __restrict__ out)
{
    __shared__ float s_x[2][TBn][PIX_PER_TILE];   // 64 KiB double buffer
    __shared__ int4 s_rp[Cn];
    __shared__ uint32_t m32[2][32 * MROW_DW];

    if (threadIdx.x < Cn) {
        s_rp[threadIdx.x] = reinterpret_cast<const int4*>(rp)[threadIdx.x];
    }

    const int b = blockIdx.x >> 6;               // 64 blocks per image
    const int pix0 = (blockIdx.x & 63) << 8;     // 256-px block range
    const int lane = threadIdx.x & 63;
    const int wv = threadIdx.x >> 6;             // wave 0..3
    const int g = threadIdx.x & 31;              // float4 group within tile
    const int o = threadIdx.x >> 5;              // plane/channel octet 0..7

    // Per-lane global src: lanes 0-31 -> plane pp, lanes 32-63 -> plane pp+1
    // (LDS dest is wave-uniform base + lane*16; rows are 512 B contiguous).
    const float* gb = x + (size_t)b * TBn * HW + (size_t)(lane >> 5) * HW
                        + pix0 + (lane & 31) * 4;

    // ---- Issue DMA for BOTH tiles up front (16 glds in flight per wave). ----
    #pragma unroll
    for (int j = 0; j < 8; ++j) {
        const int pp = wv * 16 + j * 2;          // wave wv stages planes wv*16..+15
        __builtin_amdgcn_global_load_lds((g_void*)(gb + (size_t)pp * HW),
                                         (l_void*)&s_x[0][pp][0], 16, 0, 0);
    }
    #pragma unroll
    for (int j = 0; j < 8; ++j) {
        const int pp = wv * 16 + j * 2;
        __builtin_amdgcn_global_load_lds((g_void*)(gb + (size_t)pp * HW + PIX_PER_TILE),
                                         (l_void*)&s_x[1][pp][0], 16, 0, 0);
    }

    // Wait ONLY tile 0 (8 youngest = tile 1 stays in flight across the barrier).
    // lgkmcnt(0): s_rp ds_write visibility. Raw barrier: no vmcnt(0) drain.
    asm volatile("s_waitcnt vmcnt(8) lgkmcnt(0)\n\ts_barrier" ::: "memory");
    __builtin_amdgcn_sched_barrier(0);

    #pragma unroll
    for (int t = 0; t < 2; ++t) {
        // ---- Pack tile t: planes o*8..o*8+7 for 4 pixels -> one u32. ----
        // bit 23 of the f32 encoding == (v == 1.0f) for v in {0.0, 1.0}.
        uint32_t p0 = 0, p1 = 0, p2 = 0, p3 = 0;
        #pragma unroll
        for (int i = 0; i < 8; ++i) {
            const float4 v = *reinterpret_cast<const float4*>(&s_x[t][o * 8 + i][g * 4]);
            p0 |= ((__float_as_uint(v.x) >> 23) & 1u) << i;
            p1 |= ((__float_as_uint(v.y) >> 23) & 1u) << i;
            p2 |= ((__float_as_uint(v.z) >> 23) & 1u) << i;
            p3 |= ((__float_as_uint(v.w) >> 23) & 1u) << i;
        }
        m32[t][g * MROW_DW + o] = p0 | (p1 << 8) | (p2 << 16) | (p3 << 24);

        // Make pack results visible block-wide (no vmem drain).
        asm volatile("s_waitcnt lgkmcnt(0)\n\ts_barrier" ::: "memory");
        __builtin_amdgcn_sched_barrier(0);

        // ---- Compute + store tile t: channels o*8..o*8+7. ----
        uint32_t r[8];
        #pragma unroll
        for (int i = 0; i < 8; ++i) {
            r[i] = m32[t][g * MROW_DW + i];
        }
        uint64_t m0 = 0, m1 = 0, m2 = 0, m3 = 0;
        #pragma unroll
        for (int i = 0; i < 8; ++i) {
            m0 |= (uint64_t)((r[i]      ) & 0xffu) << (i * 8);
            m1 |= (uint64_t)((r[i] >>  8) & 0xffu) << (i * 8);
            m2 |= (uint64_t)((r[i] >> 16) & 0xffu) << (i * 8);
            m3 |= (uint64_t)((r[i] >> 24) & 0xffu) << (i * 8);
        }

        const int c0 = o * 8;
        float* ob = out + (size_t)b * Cn * HW + (size_t)c0 * HW
                        + pix0 + t * PIX_PER_TILE + g * 4;

        #pragma unroll
        for (int ci = 0; ci < 8; ++ci) {
            const int4 rr = s_rp[c0 + ci];
            const unsigned i0 = (unsigned)rr.x;
            const unsigned i1 = (unsigned)rr.y;
            const unsigned i2 = (unsigned)rr.z;
            const unsigned i3 = (unsigned)rr.w;

            float4 oo;
            oo.x = (float)((unsigned)((m0 >> i0) & 1ull)
                         | ((unsigned)((m0 >> i1) & 1ull) << 1)
                         | ((unsigned)((m0 >> i2) & 1ull) << 2)
                         | ((unsigned)((m0 >> i3) & 1ull) << 3));
            oo.y = (float)((unsigned)((m1 >> i0) & 1ull)
                         | ((unsigned)((m1 >> i1) & 1ull) << 1)
                         | ((unsigned)((m1 >> i2) & 1ull) << 2)
                         | ((unsigned)((m1 >> i3) & 1ull) << 3));
            oo.z = (float)((unsigned)((m2 >> i0) & 1ull)
                         | ((unsigned)((m2 >> i1) & 1ull) << 1)
                         | ((unsigned)((m2 >> i2) & 1ull) << 2)
                         | ((unsigned)((m2 >> i3) & 1ull) << 3));
            oo.w = (float)((unsigned)((m3 >> i0) & 1ull)
                         | ((unsigned)((m3 >> i1) & 1ull) << 1)
                         | ((unsigned)((m3 >> i2) & 1ull) << 2)
                         | ((unsigned)((m3 >> i3) & 1ull) << 3));

            *reinterpret_cast<float4*>(ob + (size_t)ci * HW) = oo;
        }

        if (t == 0) {
            // Tile-0 stores just issued are the 8 youngest vmem ops; waiting
            // vmcnt(8) means: all tile-1 DMA loads have landed. Stores drain
            // later on their own. Then barrier before re-reading s_x[1]/m32.
            asm volatile("s_waitcnt vmcnt(8) lgkmcnt(0)\n\ts_barrier" ::: "memory");
            __builtin_amdgcn_sched_barrier(0);
        }
    }
}

extern "C" void kernel_launch(void* const* d_in, const int* in_sizes, int n_in,
                              void* d_out, int out_size, void* d_ws, size_t ws_size,
                              hipStream_t stream) {
    const float* x = (const float*)d_in[0];
    const int* rp = (const int*)d_in[1];
    float* out = (float*)d_out;

    constexpr int BLOCK = 256;
    rp_pack_pipe<<<BLOCKS, BLOCK, 0, stream>>>(x, rp, out);
}